// Round 15
// baseline (264.537 us; speedup 1.0000x reference)
//
#include <hip/hip_runtime.h>
#include <math.h>

#define N_NODES 50000
#define N_EDGES 800000
#define DIM_IN 64
#define DIM_HID 128
#define DIM_OUT 64
#define WROW 128   // bf16 per weight row: 256B. wt is stored PRE-SWIZZLED (see prep).

typedef __attribute__((ext_vector_type(8))) short short8;   // 8 bf16 (4 VGPRs)
typedef __attribute__((ext_vector_type(4))) float f32x4;    // MFMA accumulator

union U8 { uint4 u; short8 s; };

// RTNE float->bf16 (inputs finite) -- software path, used only in weight prep
__device__ __forceinline__ unsigned short f2bf(float f) {
    unsigned u = __float_as_uint(f);
    return (unsigned short)((u + 0x7fffu + ((u >> 16) & 1u)) >> 16);
}

// gfx950 has NO cvt_pk_bf16 builtin (learn_hip m240). Single VOP3 via asm.
__device__ __forceinline__ unsigned cvt_pk_bf16(float a, float b) {
    unsigned d;
    asm("v_cvt_pk_bf16_f32 %0, %1, %2" : "=v"(d) : "v"(a), "v"(b));
    return d;
}

__device__ __forceinline__ float exp2_fast(float a) {
#if __has_builtin(__builtin_amdgcn_exp2f)
    return __builtin_amdgcn_exp2f(a);
#else
    return __expf(a * 0.69314718f);
#endif
}

// softplus(x) = max(x,0) + log1p(exp(-|x|)); cubic log1p fit, err ~1.5e-3
__device__ __forceinline__ unsigned sp2(float x0, float x1) {
    const float L2E = 1.44269504f;
    float z0 = exp2_fast(-fabsf(x0) * L2E);
    float z1 = exp2_fast(-fabsf(x1) * L2E);
    float p0 = fmaf(fmaf(fmaf(-0.1011458f, z0, 0.2942925f), z0, -0.5f), z0, 1.0f) * z0;
    float p1 = fmaf(fmaf(fmaf(-0.1011458f, z1, 0.2942925f), z1, -0.5f), z1, 1.0f) * z1;
    return cvt_pk_bf16(fmaxf(x0, 0.0f) + p0, fmaxf(x1, 0.0f) + p1);
}

// async 16B global -> LDS DMA (compiler never auto-emits this; Common-mistake #1).
// LDS dest is WAVE-UNIFORM base; HW adds lane*16. Global src is per-lane.
__device__ __forceinline__ void load16_to_lds(const void* gsrc, void* lds) {
    auto g = (const __attribute__((address_space(1))) unsigned int*)gsrc;
    auto l = (__attribute__((address_space(3))) unsigned int*)lds;
    __builtin_amdgcn_global_load_lds(g, l, 16, 0, 0);
}

// Prep (single dispatch, replaces memset+prep):
//  - zero the output accumulator (12.8MB, grid covers it exactly)
//  - convert x to a bf16 gather table (optional)
//  - build bf16 W^T [320][128] tables, stored PRE-SWIZZLED: the 16B slot j of
//    row r lands at slot j^(r&7). Main stages chunks LINEARLY via
//    global_load_lds (rule #21: source permutation == read permutation), and
//    reads with the same XOR -> bank-conflict-free ds_read_b128.
//    Layers 1,2 additionally carry the K-permutation pi (f) matching the MFMA
//    C-layout -> frag register renaming.
template <bool DO_XBF>
__global__ void prep_all(const float* __restrict__ x,
                         const float* __restrict__ W0,
                         const float* __restrict__ W1,
                         const float* __restrict__ W2,
                         unsigned short* __restrict__ wt,
                         unsigned short* __restrict__ xbf,
                         float4* __restrict__ outz) {
    int i = blockIdx.x * blockDim.x + threadIdx.x;

    if (i < (N_NODES * DIM_OUT / 4))                 // zero out: 800000 float4
        outz[i] = make_float4(0.f, 0.f, 0.f, 0.f);

    if (DO_XBF && i < (N_NODES * DIM_IN / 4)) {      // 800000 float4 -> uint2 bf16
        float4 v = *((const float4*)x + i);
        uint2 p;
        p.x = cvt_pk_bf16(v.x, v.y);
        p.y = cvt_pk_bf16(v.z, v.w);
        *((uint2*)xbf + i) = p;
    }

    if (i < 320 * WROW) {                            // 40960 weight elements
        int row = i >> 7, s = i & 127;
        float v;
        int f = ((s >> 5) << 5) | (((s & 7) >> 2) << 4) | (((s >> 3) & 3) << 2) | (s & 3);
        if (row < 128)      v = W0[s * DIM_HID + row];          // layer 0: natural k
        else if (row < 256) v = W1[f * DIM_HID + (row - 128)];  // layer 1: permuted k
        else                v = W2[f * DIM_OUT + (row - 256)];  // layer 2: permuted k
        // pre-swizzled store position: 16B slot (s>>3) -> (s>>3)^(row&7)
        int slot = s >> 3, word = s & 7;
        wt[(row << 7) | (((slot ^ (row & 7))) << 3) | word] = f2bf(v);
    }
}

// Layers 0,1 flipped: H^T = softplus(W^T H^T + b) via mfma(A=weight, B=activation).
// Layer 2 un-flipped: O = H W2 + b2 via mfma(A=activation, B=weight); C row=edge.
//
// R14 structure (180us, best) with the staging path converted to async
// global_load_lds DMA: wt is pre-swizzled in workspace, so each 16,384B chunk
// is staged LINEARLY as 16 x 1KB DMA ops (4 calls/wave, wave-uniform LDS base,
// per-lane global src) -- no staging data-VGPRs, no swizzle VALU in the hot
// path. Reads keep the XOR slot swizzle ((kk*4+q)^(l16&7)): lanes 0..7 cover 8
// distinct 16B slots spanning all 32 banks; lanes 8..15 alias 2-way (free,
// m136). (256,4) = the never-spilled 64-reg cap; VGPR demand drops with the
// staging regs gone.
template <bool XB>
__global__ __launch_bounds__(256, 4)
void edge_mlp_mfma(const float* __restrict__ x,
                   const unsigned short* __restrict__ xbf,
                   const int* __restrict__ eidx,
                   const unsigned short* __restrict__ wt,
                   const float* __restrict__ b0,
                   const float* __restrict__ b1,
                   const float* __restrict__ b2,
                   float* __restrict__ out) {
    __shared__ unsigned short lw[64 * WROW];   // 16,384 B: one 64-row weight chunk

    const int lane = threadIdx.x & 63;
    const int w    = threadIdx.x >> 6;
    const int l16  = lane & 15;
    const int q    = lane >> 4;
    const int sx   = l16 & 7;                  // read-side swizzle key
    const int e0w  = blockIdx.x * 128 + w * 32;   // this wave's 32 edges

    int nodeR[2], nodeC[2];
#pragma unroll
    for (int m = 0; m < 2; ++m) {
        nodeR[m] = eidx[e0w + m * 16 + l16];
        nodeC[m] = eidx[N_EDGES + e0w + m * 16 + l16];
    }

    // layer-2 scatter nodes for this quad's 8 edges (L1-hot reload)
    int ns[8];
#pragma unroll
    for (int m = 0; m < 2; ++m)
#pragma unroll
        for (int r = 0; r < 4; ++r)
            ns[m * 4 + r] = eidx[e0w + m * 16 + q * 4 + r];

    // stage chunk c (pre-swizzled rows c*64..c*64+63) linearly: 16 x 1KB DMA.
    // wave w covers regions w*4..w*4+3; each call: 64 lanes x 16B = 1KB.
    const char* wtb = (const char*)wt;
    char* lwb = (char*)lw;
    auto stage = [&](int c) {
#pragma unroll
        for (int it = 0; it < 4; ++it) {
            const int reg = w * 4 + it;        // 0..15, wave-uniform
            load16_to_lds(wtb + (size_t)c * 16384 + reg * 1024 + lane * 16,
                          lwb + reg * 1024);
        }
    };

    // layer-0 B-frags: B(k=kk*32+q*8+j, edge=m*16+l16) -- issued before the
    // first stage+barrier so gather latency hides under them
    short8 hfr[2][4];
#pragma unroll
    for (int m = 0; m < 2; ++m)
#pragma unroll
        for (int kk = 0; kk < 4; ++kk) {
            int node = (kk >= 2) ? nodeC[m] : nodeR[m];
            if (XB) {
                hfr[m][kk] = *(const short8*)(xbf + (size_t)node * DIM_IN + (kk & 1) * 32 + q * 8);
            } else {
                const float* p = x + (size_t)node * DIM_IN + (kk & 1) * 32 + q * 8;
                float4 v0 = *(const float4*)p;
                float4 v1 = *(const float4*)(p + 4);
                U8 t;
                t.u.x = cvt_pk_bf16(v0.x, v0.y);
                t.u.y = cvt_pk_bf16(v0.z, v0.w);
                t.u.z = cvt_pk_bf16(v1.x, v1.y);
                t.u.w = cvt_pk_bf16(v1.z, v1.w);
                hfr[m][kk] = t.s;
            }
        }

    stage(0);
    __syncthreads();   // drains the DMA (vmcnt) + publishes LDS

    // ---- layers 0,1: H^T = softplus(W^T H^T + b), weights from LDS chunks ----
#pragma unroll
    for (int L = 0; L < 2; ++L) {
        const float* bias = L ? b1 : b0;
        unsigned d[2][8][2];
#pragma unroll
        for (int half = 0; half < 2; ++half) {
#pragma unroll
            for (int ti = 0; ti < 4; ++ti) {
                const int tiG = half * 4 + ti;
                f32x4 bb = *(const f32x4*)(bias + tiG * 16 + q * 4);  // bias on row dim
                f32x4 a0 = bb, a1 = bb;
                const unsigned short* rowb = lw + (ti * 16 + l16) * WROW;
                short8 wf[4];
#pragma unroll
                for (int kk = 0; kk < 4; ++kk)
                    wf[kk] = *(const short8*)(rowb + ((kk * 4 + q) ^ sx) * 8); // ds_read_b128, swizzled
#pragma unroll
                for (int kk = 0; kk < 4; ++kk) {
                    a0 = __builtin_amdgcn_mfma_f32_16x16x32_bf16(wf[kk], hfr[0][kk], a0, 0, 0, 0);
                    a1 = __builtin_amdgcn_mfma_f32_16x16x32_bf16(wf[kk], hfr[1][kk], a1, 0, 0, 0);
                }
                // per-ti epilogue keeps acc liveness at 8 VGPRs
                d[0][tiG][0] = sp2(a0[0], a0[1]);
                d[0][tiG][1] = sp2(a0[2], a0[3]);
                d[1][tiG][0] = sp2(a1[0], a1[1]);
                d[1][tiG][1] = sp2(a1[2], a1[3]);
            }
            // swap in the next 64-row chunk (the last one is L2's table)
            __syncthreads();                  // all waves done reading lw
            stage(L * 2 + half + 1);
            __syncthreads();
        }
        // next-layer frags: pure register renaming (weights carry pi)
#pragma unroll
        for (int m = 0; m < 2; ++m)
#pragma unroll
            for (int kk = 0; kk < 4; ++kk) {
                U8 t;
                t.u.x = d[m][2 * kk][0];
                t.u.y = d[m][2 * kk][1];
                t.u.z = d[m][2 * kk + 1][0];
                t.u.w = d[m][2 * kk + 1][1];
                hfr[m][kk] = t.s;
            }
    }

    // ---- layer 2 (un-flipped): O = H W2 + b2; lw holds chunk 4 (rows 256..319).
    // All loads complete before any atomic issues (vmcnt is in-order).
    {
        f32x4 acc[4][2];
#pragma unroll
        for (int ti = 0; ti < 4; ++ti) {
            float bv = b2[ti * 16 + l16];                    // bias on col dim
            f32x4 a0 = (f32x4){bv, bv, bv, bv};
            f32x4 a1 = a0;
            const unsigned short* rowb = lw + (ti * 16 + l16) * WROW;
            short8 wf[4];
#pragma unroll
            for (int kk = 0; kk < 4; ++kk)
                wf[kk] = *(const short8*)(rowb + ((kk * 4 + q) ^ sx) * 8);  // ds_read_b128, swizzled
#pragma unroll
            for (int kk = 0; kk < 4; ++kk) {
                a0 = __builtin_amdgcn_mfma_f32_16x16x32_bf16(hfr[0][kk], wf[kk], a0, 0, 0, 0);
                a1 = __builtin_amdgcn_mfma_f32_16x16x32_bf16(hfr[1][kk], wf[kk], a1, 0, 0, 0);
            }
            acc[ti][0] = a0;
            acc[ti][1] = a1;
        }

        // terminal atomic burst: fire-and-forget, nothing waits on the acks.
        // each instruction covers full 64B sectors (quad-uniform node, l16
        // lanes contiguous), 4 transactions/instr.
#pragma unroll
        for (int ti = 0; ti < 4; ++ti)
#pragma unroll
            for (int r = 0; r < 4; ++r) {
                atomicAdd(out + (size_t)ns[r] * DIM_OUT + ti * 16 + l16, acc[ti][0][r]);
                atomicAdd(out + (size_t)ns[4 + r] * DIM_OUT + ti * 16 + l16, acc[ti][1][r]);
            }
    }
}

extern "C" void kernel_launch(void* const* d_in, const int* in_sizes, int n_in,
                              void* d_out, int out_size, void* d_ws, size_t ws_size,
                              hipStream_t stream) {
    const float* x  = (const float*)d_in[0];
    const int*   ei = (const int*)d_in[1];
    const float* W0 = (const float*)d_in[2];
    const float* b0 = (const float*)d_in[3];
    const float* W1 = (const float*)d_in[4];
    const float* b1 = (const float*)d_in[5];
    const float* W2 = (const float*)d_in[6];
    const float* b2 = (const float*)d_in[7];
    float* out = (float*)d_out;

    unsigned short* wt = (unsigned short*)d_ws;
    const size_t WT_BYTES = (size_t)320 * WROW * sizeof(unsigned short);  // 81920 (256-aligned)
    unsigned short* xbf = (unsigned short*)((char*)d_ws + WT_BYTES);
    const size_t need = WT_BYTES + (size_t)N_NODES * DIM_IN * sizeof(unsigned short); // ~6.5 MB

    const int PREP_BLOCKS = (N_NODES * DIM_IN / 4 + 255) / 256;   // 3125: covers zero/xbf/wt

    if (ws_size >= need) {
        // TWO dispatches total: fused {zero + xbf + weights} prep, then main.
        prep_all<true><<<PREP_BLOCKS, 256, 0, stream>>>(
            x, W0, W1, W2, wt, xbf, (float4*)out);
        edge_mlp_mfma<true><<<N_EDGES / 128, 256, 0, stream>>>(
            x, xbf, ei, wt, b0, b1, b2, out);
    } else {
        // fallback: fused {zero + weights} prep, f32 x gather
        prep_all<false><<<PREP_BLOCKS, 256, 0, stream>>>(
            x, W0, W1, W2, wt, nullptr, (float4*)out);
        edge_mlp_mfma<false><<<N_EDGES / 128, 256, 0, stream>>>(
            x, nullptr, ei, wt, b0, b1, b2, out);
    }
}

// Round 16
// 259.852 us; speedup vs baseline: 1.0180x; 1.0180x over previous
//
#include <hip/hip_runtime.h>
#include <math.h>

#define N_NODES 50000
#define N_EDGES 800000
#define DIM_IN 64
#define DIM_HID 128
#define DIM_OUT 64
#define WROW 128   // bf16 per weight row: 256B exactly (no pad; XOR swizzle handles banks)

typedef __attribute__((ext_vector_type(8))) short short8;   // 8 bf16 (4 VGPRs)
typedef __attribute__((ext_vector_type(4))) float f32x4;    // MFMA accumulator

union U8 { uint4 u; short8 s; };

// RTNE float->bf16 (inputs finite) -- software path, used only in weight prep
__device__ __forceinline__ unsigned short f2bf(float f) {
    unsigned u = __float_as_uint(f);
    return (unsigned short)((u + 0x7fffu + ((u >> 16) & 1u)) >> 16);
}

// gfx950 has NO cvt_pk_bf16 builtin (learn_hip m240). Single VOP3 via asm.
// lo = a, hi = b; RTNE (default round mode) == the software f2bf path.
__device__ __forceinline__ unsigned cvt_pk_bf16(float a, float b) {
    unsigned d;
    asm("v_cvt_pk_bf16_f32 %0, %1, %2" : "=v"(d) : "v"(a), "v"(b));
    return d;
}

__device__ __forceinline__ float exp2_fast(float a) {
#if __has_builtin(__builtin_amdgcn_exp2f)
    return __builtin_amdgcn_exp2f(a);
#else
    return __expf(a * 0.69314718f);
#endif
}

// softplus(x) = max(x,0) + log1p(exp(-|x|)); log1p(z) ~ z*(1 + z*(-0.5 + z*(A + z*B)))
// cubic fit on z in (0,1], max abs err ~1.5e-3 (below bf16 quantization of H)
__device__ __forceinline__ unsigned sp2(float x0, float x1) {
    const float L2E = 1.44269504f;
    float z0 = exp2_fast(-fabsf(x0) * L2E);
    float z1 = exp2_fast(-fabsf(x1) * L2E);
    float p0 = fmaf(fmaf(fmaf(-0.1011458f, z0, 0.2942925f), z0, -0.5f), z0, 1.0f) * z0;
    float p1 = fmaf(fmaf(fmaf(-0.1011458f, z1, 0.2942925f), z1, -0.5f), z1, 1.0f) * z1;
    return cvt_pk_bf16(fmaxf(x0, 0.0f) + p0, fmaxf(x1, 0.0f) + p1);
}

// Prep: convert x to a bf16 table (optional) + build bf16 W^T [320][128] table
// (layers 1,2 carry the K-permutation pi matching the MFMA C-layout -> frag
// renaming). Output zeroing is a separate hipMemsetAsync (DMA path).
template <bool DO_XBF>
__global__ void prep_all(const float* __restrict__ x,
                         const float* __restrict__ W0,
                         const float* __restrict__ W1,
                         const float* __restrict__ W2,
                         unsigned short* __restrict__ wt,
                         unsigned short* __restrict__ xbf) {
    int i = blockIdx.x * blockDim.x + threadIdx.x;

    if (DO_XBF && i < (N_NODES * DIM_IN / 4)) {      // 800000 float4 -> uint2 bf16
        float4 v = *((const float4*)x + i);
        uint2 p;
        p.x = cvt_pk_bf16(v.x, v.y);
        p.y = cvt_pk_bf16(v.z, v.w);
        *((uint2*)xbf + i) = p;
    }

    if (i < 320 * WROW) {                            // 40960 weight elements
        int row = i >> 7, s = i & 127;
        float v;
        int f = ((s >> 5) << 5) | (((s & 7) >> 2) << 4) | (((s >> 3) & 3) << 2) | (s & 3);
        if (row < 128)      v = W0[s * DIM_HID + row];          // layer 0: natural k
        else if (row < 256) v = W1[f * DIM_HID + (row - 128)];  // layer 1: permuted k
        else                v = W2[f * DIM_OUT + (row - 256)];  // layer 2: permuted k
        wt[i] = f2bf(v);
    }
}

// Layers 0,1 flipped: H^T = softplus(W^T H^T + b) via mfma(A=weight, B=activation).
// Layer 2 un-flipped: O = H W2 + b2 via mfma(A=activation, B=weight); C row=edge.
//
// REGISTER-BUDGET round: R14 (this exact body at (256,4)) compiles at exactly
// its 64-reg cap (cap ~= 256/min_waves across all measured points); the body's
// ideal liveness (hfr 32 + d up to 32 + wf 16 transient + acc 8) is ~80+, so
// the scheduler cannot hoist ds_reads/bias loads across ti phases -- every one
// of the 20 ti iterations eats a naked wait. (256,3) raises the cap to ~85
// (no candidate semantics lowers it; need ~64-72 -> no spill risk) with no
// occupancy cost (85 regs still permits 16 waves/CU; achieved is ~12.5 and
// R11 proved resources don't move it). Single factor vs R14.
// Weight chunks: five 64-row x 256B chunks; L0 = chunks 0,1; L1 = 2,3; L2 = 4.
// XOR slot swizzle: 16B-slot col of row r stored at col^(r&7); read lanes
// (l16,q) at fixed kk hit bank-group (4kk+q)^(l16&7) -> uniform 8 lanes/group
// = width-limited minimum. Staging writes: 2 dwords/bank = free.
template <bool XB>
__global__ __launch_bounds__(256, 3)
void edge_mlp_mfma(const float* __restrict__ x,
                   const unsigned short* __restrict__ xbf,
                   const int* __restrict__ eidx,
                   const unsigned short* __restrict__ wt,
                   const float* __restrict__ b0,
                   const float* __restrict__ b1,
                   const float* __restrict__ b2,
                   float* __restrict__ out) {
    __shared__ unsigned short lw[64 * WROW];   // 16,384 B: one 64-row weight chunk

    const int lane = threadIdx.x & 63;
    const int w    = threadIdx.x >> 6;
    const int l16  = lane & 15;
    const int q    = lane >> 4;
    const int sx   = l16 & 7;                  // read-side swizzle key
    const int e0w  = blockIdx.x * 128 + w * 32;   // this wave's 32 edges

    int nodeR[2], nodeC[2];
#pragma unroll
    for (int m = 0; m < 2; ++m) {
        nodeR[m] = eidx[e0w + m * 16 + l16];
        nodeC[m] = eidx[N_EDGES + e0w + m * 16 + l16];
    }

    // layer-2 scatter nodes for this quad's 8 edges (L1-hot reload)
    int ns[8];
#pragma unroll
    for (int m = 0; m < 2; ++m)
#pragma unroll
        for (int r = 0; r < 4; ++r)
            ns[m * 4 + r] = eidx[e0w + m * 16 + q * 4 + r];

    // layer-0 B-frags: B(k=kk*32+q*8+j, edge=m*16+l16) -- issued before the
    // first stage+barrier so gather latency hides under them
    short8 hfr[2][4];
#pragma unroll
    for (int m = 0; m < 2; ++m)
#pragma unroll
        for (int kk = 0; kk < 4; ++kk) {
            int node = (kk >= 2) ? nodeC[m] : nodeR[m];
            if (XB) {
                hfr[m][kk] = *(const short8*)(xbf + (size_t)node * DIM_IN + (kk & 1) * 32 + q * 8);
            } else {
                const float* p = x + (size_t)node * DIM_IN + (kk & 1) * 32 + q * 8;
                float4 v0 = *(const float4*)p;
                float4 v1 = *(const float4*)(p + 4);
                U8 t;
                t.u.x = cvt_pk_bf16(v0.x, v0.y);
                t.u.y = cvt_pk_bf16(v0.z, v0.w);
                t.u.z = cvt_pk_bf16(v1.x, v1.y);
                t.u.w = cvt_pk_bf16(v1.z, v1.w);
                hfr[m][kk] = t.s;
            }
        }

    // stage chunk c (weight rows c*64..c*64+63): 1024 uint4 = 4 exact rounds.
    // LDS slot-swizzled: source 16B-slot col of row goes to col ^ (row&7).
    auto stage = [&](int c) {
        const uint4* src = (const uint4*)(wt + (size_t)c * 64 * WROW);
        uint4* dst = (uint4*)lw;
#pragma unroll
        for (int it = 0; it < 4; ++it) {
            int i = threadIdx.x + it * 256;        // 0..1023
            int row = i >> 4, col = i & 15;
            dst[(row << 4) | (col ^ (row & 7))] = src[i];
        }
    };

    stage(0);
    __syncthreads();

    // ---- layers 0,1: H^T = softplus(W^T H^T + b), weights from LDS chunks ----
#pragma unroll
    for (int L = 0; L < 2; ++L) {
        const float* bias = L ? b1 : b0;
        unsigned d[2][8][2];
#pragma unroll
        for (int half = 0; half < 2; ++half) {
#pragma unroll
            for (int ti = 0; ti < 4; ++ti) {
                const int tiG = half * 4 + ti;
                f32x4 bb = *(const f32x4*)(bias + tiG * 16 + q * 4);  // bias on row dim
                f32x4 a0 = bb, a1 = bb;
                const unsigned short* rowb = lw + (ti * 16 + l16) * WROW;
                short8 wf[4];
#pragma unroll
                for (int kk = 0; kk < 4; ++kk)
                    wf[kk] = *(const short8*)(rowb + ((kk * 4 + q) ^ sx) * 8); // ds_read_b128, swizzled
#pragma unroll
                for (int kk = 0; kk < 4; ++kk) {
                    a0 = __builtin_amdgcn_mfma_f32_16x16x32_bf16(wf[kk], hfr[0][kk], a0, 0, 0, 0);
                    a1 = __builtin_amdgcn_mfma_f32_16x16x32_bf16(wf[kk], hfr[1][kk], a1, 0, 0, 0);
                }
                // per-ti epilogue keeps acc liveness at 8 VGPRs
                d[0][tiG][0] = sp2(a0[0], a0[1]);
                d[0][tiG][1] = sp2(a0[2], a0[3]);
                d[1][tiG][0] = sp2(a1[0], a1[1]);
                d[1][tiG][1] = sp2(a1[2], a1[3]);
            }
            // swap in the next 64-row chunk (the last one is L2's table)
            __syncthreads();                  // all waves done reading lw
            stage(L * 2 + half + 1);
            __syncthreads();
        }
        // next-layer frags: pure register renaming (weights carry pi)
#pragma unroll
        for (int m = 0; m < 2; ++m)
#pragma unroll
            for (int kk = 0; kk < 4; ++kk) {
                U8 t;
                t.u.x = d[m][2 * kk][0];
                t.u.y = d[m][2 * kk][1];
                t.u.z = d[m][2 * kk + 1][0];
                t.u.w = d[m][2 * kk + 1][1];
                hfr[m][kk] = t.s;
            }
    }

    // ---- layer 2 (un-flipped): O = H W2 + b2; lw holds chunk 4 (rows 256..319).
    // All loads complete before any atomic issues (vmcnt is in-order).
    {
        f32x4 acc[4][2];
#pragma unroll
        for (int ti = 0; ti < 4; ++ti) {
            float bv = b2[ti * 16 + l16];                    // bias on col dim
            f32x4 a0 = (f32x4){bv, bv, bv, bv};
            f32x4 a1 = a0;
            const unsigned short* rowb = lw + (ti * 16 + l16) * WROW;
            short8 wf[4];
#pragma unroll
            for (int kk = 0; kk < 4; ++kk)
                wf[kk] = *(const short8*)(rowb + ((kk * 4 + q) ^ sx) * 8);  // ds_read_b128, swizzled
#pragma unroll
            for (int kk = 0; kk < 4; ++kk) {
                a0 = __builtin_amdgcn_mfma_f32_16x16x32_bf16(hfr[0][kk], wf[kk], a0, 0, 0, 0);
                a1 = __builtin_amdgcn_mfma_f32_16x16x32_bf16(hfr[1][kk], wf[kk], a1, 0, 0, 0);
            }
            acc[ti][0] = a0;
            acc[ti][1] = a1;
        }

        // terminal atomic burst: fire-and-forget, nothing waits on the acks.
        // each instruction covers full 64B sectors (quad-uniform node, l16 lanes
        // contiguous), 4 transactions/instr.
#pragma unroll
        for (int ti = 0; ti < 4; ++ti)
#pragma unroll
            for (int r = 0; r < 4; ++r) {
                atomicAdd(out + (size_t)ns[r] * DIM_OUT + ti * 16 + l16, acc[ti][0][r]);
                atomicAdd(out + (size_t)ns[4 + r] * DIM_OUT + ti * 16 + l16, acc[ti][1][r]);
            }
    }
}

extern "C" void kernel_launch(void* const* d_in, const int* in_sizes, int n_in,
                              void* d_out, int out_size, void* d_ws, size_t ws_size,
                              hipStream_t stream) {
    const float* x  = (const float*)d_in[0];
    const int*   ei = (const int*)d_in[1];
    const float* W0 = (const float*)d_in[2];
    const float* b0 = (const float*)d_in[3];
    const float* W1 = (const float*)d_in[4];
    const float* b1 = (const float*)d_in[5];
    const float* W2 = (const float*)d_in[6];
    const float* b2 = (const float*)d_in[7];
    float* out = (float*)d_out;

    unsigned short* wt = (unsigned short*)d_ws;
    const size_t WT_BYTES = (size_t)320 * WROW * sizeof(unsigned short);  // 81920 (256-aligned)
    unsigned short* xbf = (unsigned short*)((char*)d_ws + WT_BYTES);
    const size_t need = WT_BYTES + (size_t)N_NODES * DIM_IN * sizeof(unsigned short); // ~6.5 MB

    hipMemsetAsync(out, 0, (size_t)N_NODES * DIM_OUT * sizeof(float), stream);

    if (ws_size >= need) {
        prep_all<true><<<(N_NODES * DIM_IN / 4 + 255) / 256, 256, 0, stream>>>(
            x, W0, W1, W2, wt, xbf);
        edge_mlp_mfma<true><<<N_EDGES / 128, 256, 0, stream>>>(
            x, xbf, ei, wt, b0, b1, b2, out);
    } else {
        // fallback: weights-only prep, f32 x gather
        prep_all<false><<<(320 * WROW + 255) / 256, 256, 0, stream>>>(
            x, W0, W1, W2, wt, nullptr);
        edge_mlp_mfma<false><<<N_EDGES / 128, 256, 0, stream>>>(
            x, nullptr, ei, wt, b0, b1, b2, out);
    }
}